// Round 4
// baseline (5386.000 us; speedup 1.0000x reference)
//
#include <hip/hip_runtime.h>
#include <math.h>

// ---------------------------------------------------------------------------
// TransformerDecoder: persistent-kernel KV-cache decode, dataflow-synced.
// B=8, S_SRC=256, T=64, D=256, H=8, HD=32, DFF=1024, NC=128, L=2. fp32.
// 64 blocks = 8 independent batch streams x 8 sub-roles (head h / col-group).
// Producer->consumer flag sync (relaxed agent atomics); projections fused
// into producers as per-head/per-group partials, reduced by consumers.
// 7 hops per decode step (was 14 global barriers).
// ---------------------------------------------------------------------------

#define EPS_ 1e-5f
#define SCALE_ 0.17677669529663687f   // 1/sqrt(32)
#define BNS 0.99999500003749969f      // 1/sqrt(1+1e-5)

#define DEV __device__ __forceinline__

DEV float ald(const float* p) {
  return __hip_atomic_load(p, __ATOMIC_RELAXED, __HIP_MEMORY_SCOPE_AGENT);
}
DEV void ast(float* p, float v) {
  __hip_atomic_store(p, v, __ATOMIC_RELAXED, __HIP_MEMORY_SCOPE_AGENT);
}
DEV int aldi(const int* p) {
  return __hip_atomic_load(p, __ATOMIC_RELAXED, __HIP_MEMORY_SCOPE_AGENT);
}
DEV void asti(int* p, int v) {
  __hip_atomic_store(p, v, __ATOMIC_RELAXED, __HIP_MEMORY_SCOPE_AGENT);
}

DEV float wsum(float v) {
#pragma unroll
  for (int o = 32; o; o >>= 1) v += __shfl_xor(v, o, 64);
  return v;
}
DEV float wmax(float v) {
#pragma unroll
  for (int o = 32; o; o >>= 1) v = fmaxf(v, __shfl_xor(v, o, 64));
  return v;
}

DEV float dot256(const float* a, const float* __restrict__ w) {
  const float4* a4 = (const float4*)a;
  const float4* w4 = (const float4*)w;
  float acc = 0.f;
#pragma unroll 16
  for (int i = 0; i < 64; ++i) {
    float4 av = a4[i], wv = w4[i];
    acc += av.x * wv.x + av.y * wv.y + av.z * wv.z + av.w * wv.w;
  }
  return acc;
}

// In-place LayerNorm of a 256-float LDS row; 256 threads. Each thread only
// touches its own element + shfl reductions, so no pre-sync needed.
DEV void ln_row(float* xs, const float* __restrict__ g, const float* __restrict__ bb,
                float* red) {
  int tid = threadIdx.x, wid = tid >> 6, lane = tid & 63;
  float v = xs[tid];
  float s = wsum(v), s2 = wsum(v * v);
  if (lane == 0) { red[wid] = s; red[4 + wid] = s2; }
  __syncthreads();
  float S = red[0] + red[1] + red[2] + red[3];
  float S2 = red[4] + red[5] + red[6] + red[7];
  float m = S * (1.f / 256.f);
  float rs = rsqrtf(S2 * (1.f / 256.f) - m * m + EPS_);
  __syncthreads();
  xs[tid] = (v - m) * rs * g[tid] + bb[tid];
  __syncthreads();
}

// wait until f[0..n-1] >= seq (first n lanes poll), then block-converge.
DEV void waitn(const int* f, int n, int seq) {
  if (threadIdx.x < n) { while (aldi(f + threadIdx.x) < seq) {} }
  __syncthreads();
}

// one-time global barrier for the prologue (publishes normal-store tables).
DEV void gbar(int* bar, int blk, int tid, int& mybar) {
  __syncthreads();
  ++mybar;
  if (blk == 0) {
    if (tid == 0) __threadfence();
    if (tid > 0 && tid < 64) { while (aldi(&bar[tid]) < mybar) {} }
    __syncthreads();
    if (tid == 0) asti(&bar[64], mybar);
    asm volatile("" ::: "memory");
  } else {
    if (tid == 0) {
      __threadfence();
      asti(&bar[blk], mybar);
      while (aldi(&bar[64]) < mybar) {}
    }
    asm volatile("" ::: "memory");
  }
  __syncthreads();
}

// ---------------------------------------------------------------------------

__global__ void __launch_bounds__(256) k_decode(
    const float* __restrict__ enc, const float* __restrict__ emb_w,
    const float* __restrict__ emb_b,
    const float* __restrict__ sa_wqkv, const float* __restrict__ sa_bqkv,
    const float* __restrict__ sa_wo, const float* __restrict__ sa_bo,
    const float* __restrict__ ca_wqkv, const float* __restrict__ ca_bqkv,
    const float* __restrict__ ca_wo, const float* __restrict__ ca_bo,
    const float* __restrict__ ln1_g, const float* __restrict__ ln1_b,
    const float* __restrict__ ln2_g, const float* __restrict__ ln2_b,
    const float* __restrict__ ffn_w1, const float* __restrict__ ffn_b1,
    const float* __restrict__ ffn_w2, const float* __restrict__ ffn_b2,
    const float* __restrict__ ln3_g, const float* __restrict__ ln3_b,
    const float* __restrict__ op_w1, const float* __restrict__ op_b1,
    const float* __restrict__ bn_g, const float* __restrict__ bn_b,
    const float* __restrict__ op_w2, const float* __restrict__ op_b2,
    int* bar, int* f1, int* f2, int* f3, int* f5,
    float* pe, float* mk, float* mvv, float* kc, float* vc,
    float* x0, float* r1red, float* r2red, float* r3red,
    float* p1, float* p2, float* p3, float* outp) {
  __shared__ __align__(16) float big[4096];   // 16 KB, reused per stage
  float* xs  = big;                        // 256
  float* rr  = big + 256;                  // 256
  float* aux = big + 512;                  // 256
  float* hh  = big + 768;                  // 128
  float* ov  = big + 896;                  // 128 (qv/kt/vt or qc/oc)
  float* sc  = big + 1024;                 // 64
  float (*part)[32] = (float(*)[32])(big + 1088);  // [8][32]
  float* red = big + 1344;                 // 16

  const int blk = blockIdx.x, tid = threadIdx.x;
  const int b = blk >> 3, sub = blk & 7;
  int mybar = 0;

  // ---- prologue: pe table, cross-attn mem K/V, x0 + f5 init ----
  {
    float div = expf((float)(tid & ~1) * (-9.210340371976184f / 256.f));
    float aarg = (float)blk * div;
    pe[blk * 256 + tid] = (tid & 1) ? cosf(aarg) : sinf(aarg);

    for (int vb = blk; vb < 256; vb += 64) {
      int l = vb >> 7, bb2 = (vb >> 4) & 7, s0 = (vb & 15) * 16;
      const float* Wl = ca_wqkv + (size_t)l * 768 * 256;
      for (int i = tid; i < 4096; i += 256)
        big[i] = enc[(size_t)(bb2 * 256 + s0 + (i >> 8)) * 256 + (i & 255)];
      __syncthreads();
      for (int half = 0; half < 2; ++half) {
        const float4* wr = (const float4*)(Wl + (size_t)(256 + half * 256 + tid) * 256);
        float acc[16];
#pragma unroll
        for (int s = 0; s < 16; ++s) acc[s] = 0.f;
        for (int i = 0; i < 64; ++i) {
          float4 w = wr[i];
#pragma unroll
          for (int s = 0; s < 16; ++s) {
            float4 av = ((const float4*)(big + s * 256))[i];
            acc[s] += av.x * w.x + av.y * w.y + av.z * w.z + av.w * w.w;
          }
        }
        float bias = ca_bqkv[l * 768 + 256 + half * 256 + tid];
        float* dst = half ? mvv : mk;
        int h2 = tid >> 5, hd = tid & 31;
        for (int s = 0; s < 16; ++s)
          dst[((size_t)((l * 8 + bb2) * 8 + h2) * 256 + (s0 + s)) * 32 + hd] = acc[s] + bias;
      }
      __syncthreads();
    }
    if (sub == 0) {
      // x0 for t=0: decoder buf is zeros -> x0 = emb_b + pe[0] (= 0/1 alternating)
      ast(x0 + b * 256 + tid, emb_b[tid] + ((tid & 1) ? 1.f : 0.f));
      __syncthreads();
      if (tid == 0) asti(f5 + b, 1);
    }
  }
  gbar(bar, blk, tid, mybar);   // publish pe/mk/mv (normal stores)

  // ---- 64 decode steps, 7 flag-hops each ----
  for (int t = 0; t < 64; ++t) {
    for (int l = 0; l < 2; ++l) {
      const int u = t * 2 + l, seq = u + 1;

      // ======== S1: self-attn + out-proj partial; role (b, h=sub) ========
      {
        const int h = sub;
        if (l == 0) {
          waitn(f5 + b, 1, t + 1);
          xs[tid] = ald(x0 + b * 256 + tid);
          __syncthreads();
        } else {
          waitn(f3 + b * 8, 8, u);  // f3 of (t, l=0) carries seq u
          rr[tid] = ald(r2red + 0 * 2048 + b * 256 + tid);
          __syncthreads();
          ln_row(rr, ln2_g, ln2_b, red);          // LN2, layer 0 params
          float s = 0.f;
#pragma unroll
          for (int cg = 0; cg < 8; ++cg) s += ald(p3 + (cg * 8 + b) * 256 + tid);
          float r3v = rr[tid] + s + ffn_b2[tid];  // r3 (pre-LN3), layer 0
          if (h == 0) ast(r3red + b * 256 + tid, r3v);
          xs[tid] = r3v;
          ln_row(xs, ln3_g, ln3_b, red);          // LN3, layer 0 params
        }
        // qkv for current token, cache append
        const float* W = sa_wqkv + (size_t)l * 768 * 256;
        const float* bq = sa_bqkv + l * 768;
        if (tid < 96) {
          int which = tid >> 5, j = tid & 31;
          int row = which * 256 + h * 32 + j;
          float acc = dot256(xs, W + (size_t)row * 256) + bq[row];
          if (which == 0) ov[j] = acc;
          else {
            float* cache = (which == 1 ? kc : vc) + (size_t)l * 131072 +
                           ((size_t)(b * 8 + h) * 64 + t) * 32 + j;
            *cache = acc;  // block-private: normal store
            if (which == 1) ov[32 + j] = acc; else ov[64 + j] = acc;
          }
        }
        __syncthreads();
        // causal scores over keys 0..t
        if (tid < 64) {
          float s = -3.0e38f;
          if (tid <= t) {
            const float* kr = (tid == t) ? (ov + 32)
                : kc + (size_t)l * 131072 + ((size_t)(b * 8 + h) * 64 + tid) * 32;
            float a = 0.f;
#pragma unroll
            for (int i = 0; i < 32; ++i) a += ov[i] * kr[i];
            s = a * SCALE_;
          }
          float mx = wmax(s);
          float e = (tid <= t) ? expf(s - mx) : 0.f;
          float sm = wsum(e);
          sc[tid] = e / sm;
        }
        __syncthreads();
        // PV
        {
          int g = tid >> 5, lane = tid & 31;
          float a = 0.f;
          int k0 = g * 8, k1 = k0 + 8 < t + 1 ? k0 + 8 : t + 1;
          for (int k = k0; k < k1; ++k) {
            const float* vr = (k == t) ? (ov + 64)
                : vc + (size_t)l * 131072 + ((size_t)(b * 8 + h) * 64 + k) * 32;
            a += sc[k] * vr[lane];
          }
          part[g][lane] = a;
        }
        __syncthreads();
        if (tid < 32) {
          float o = 0.f;
#pragma unroll
          for (int gg = 0; gg < 8; ++gg) o += part[gg][tid];
          aux[tid] = o;
        }
        __syncthreads();
        // out-proj partial: p1[h][b][c] = o_h . saWo[c, h*32..]
        {
          const float4* w4 = (const float4*)(sa_wo + (size_t)l * 65536 +
                                             (size_t)tid * 256 + h * 32);
          const float4* o4 = (const float4*)aux;
          float acc = 0.f;
#pragma unroll
          for (int i = 0; i < 8; ++i) {
            float4 w = w4[i], o = o4[i];
            acc += w.x * o.x + w.y * o.y + w.z * o.z + w.w * o.w;
          }
          ast(p1 + (h * 8 + b) * 256 + tid, acc);
        }
        __syncthreads();   // drains vmcnt -> data visible before flag
        if (tid == 0) asti(f1 + b * 8 + h, seq);
      }

      // ======== S2: reduce p1, cross-attn + proj partial; role (b, h=sub) ========
      {
        const int h = sub;
        waitn(f1 + b * 8, 8, seq);
        if (l == 0) {
          rr[tid] = ald(x0 + b * 256 + tid);
          __syncthreads();
        } else {
          rr[tid] = ald(r3red + b * 256 + tid);
          ln_row(rr, ln3_g, ln3_b, red);   // LN3, layer-0 params
        }
        float s = 0.f;
#pragma unroll
        for (int h2 = 0; h2 < 8; ++h2) s += ald(p1 + (h2 * 8 + b) * 256 + tid);
        float r1v = rr[tid] + s + sa_bo[l * 256 + tid];
        if (h == 0) ast(r1red + b * 256 + tid, r1v);
        xs[tid] = r1v;
        ln_row(xs, ln1_g + l * 256, ln1_b + l * 256, red);
        // qc for head h
        if (tid < 32) {
          int row = h * 32 + tid;
          ov[tid] = dot256(xs, ca_wqkv + (size_t)l * 768 * 256 + (size_t)row * 256)
                    + ca_bqkv[l * 768 + row];
        }
        __syncthreads();
        // scores over 256 memory positions
        const float* kb = mk + (size_t)l * 524288 + (size_t)(b * 8 + h) * 8192;
        float a = 0.f;
        {
          const float4* kr = (const float4*)(kb + tid * 32);
          const float4* qr = (const float4*)ov;
#pragma unroll
          for (int i = 0; i < 8; ++i) {
            float4 k4 = kr[i], q4 = qr[i];
            a += k4.x * q4.x + k4.y * q4.y + k4.z * q4.z + k4.w * q4.w;
          }
        }
        float sv = a * SCALE_;
        int wid = tid >> 6, lane = tid & 63;
        float mx = wmax(sv);
        if (lane == 0) red[wid] = mx;
        __syncthreads();
        mx = fmaxf(fmaxf(red[0], red[1]), fmaxf(red[2], red[3]));
        float e = expf(sv - mx);
        float sm = wsum(e);
        if (lane == 0) red[4 + wid] = sm;
        __syncthreads();
        sm = red[4] + red[5] + red[6] + red[7];
        aux[tid] = e / sm;
        __syncthreads();
        // PV
        {
          int g = tid >> 5, lane2 = tid & 31;
          const float* vb = mvv + (size_t)l * 524288 + (size_t)(b * 8 + h) * 8192;
          float acc = 0.f;
          for (int s2 = g * 32; s2 < g * 32 + 32; ++s2)
            acc += aux[s2] * vb[s2 * 32 + lane2];
          part[g][lane2] = acc;
        }
        __syncthreads();
        if (tid < 32) {
          float o = 0.f;
#pragma unroll
          for (int gg = 0; gg < 8; ++gg) o += part[gg][tid];
          ov[32 + tid] = o;
        }
        __syncthreads();
        // proj partial through ca_wo
        {
          const float4* w4 = (const float4*)(ca_wo + (size_t)l * 65536 +
                                             (size_t)tid * 256 + h * 32);
          const float4* o4 = (const float4*)(ov + 32);
          float acc = 0.f;
#pragma unroll
          for (int i = 0; i < 8; ++i) {
            float4 w = w4[i], o = o4[i];
            acc += w.x * o.x + w.y * o.y + w.z * o.z + w.w * o.w;
          }
          ast(p2 + (h * 8 + b) * 256 + tid, acc);
        }
        __syncthreads();
        if (tid == 0) asti(f2 + b * 8 + h, seq);
      }

      // ======== S3: reduce p2, FFN1 + FFN2-partial; role (b, cg=sub) ========
      {
        const int cg = sub;
        waitn(f2 + b * 8, 8, seq);
        rr[tid] = ald(r1red + b * 256 + tid);
        ln_row(rr, ln1_g + l * 256, ln1_b + l * 256, red);  // rr = LN1(r1)
        float s = 0.f;
#pragma unroll
        for (int h2 = 0; h2 < 8; ++h2) s += ald(p2 + (h2 * 8 + b) * 256 + tid);
        float r2v = rr[tid] + s + ca_bo[l * 256 + tid];
        if (cg == 0) ast(r2red + l * 2048 + b * 256 + tid, r2v);
        xs[tid] = r2v;
        ln_row(xs, ln2_g + l * 256, ln2_b + l * 256, red);  // xs = LN2(r2)
        // FFN1: 128 cols for this cg, 2-way K-split
        {
          int j = tid >> 1, kp = tid & 1, c = cg * 128 + j;
          const float4* a4 = (const float4*)(xs + kp * 128);
          const float4* w4 = (const float4*)(ffn_w1 + (size_t)l * 262144 +
                                             (size_t)c * 256 + kp * 128);
          float acc = 0.f;
#pragma unroll
          for (int i = 0; i < 32; ++i) {
            float4 av = a4[i], wv = w4[i];
            acc += av.x * wv.x + av.y * wv.y + av.z * wv.z + av.w * wv.w;
          }
          acc += __shfl_down(acc, 1, 64);
          if (kp == 0) hh[j] = fmaxf(acc + ffn_b1[l * 1024 + c], 0.f);
        }
        __syncthreads();
        // FFN2 partial over this cg's 128-wide k-slice, all 256 cols
        {
          const float4* h4 = (const float4*)hh;
          const float4* w4 = (const float4*)(ffn_w2 + (size_t)l * 262144 +
                                             (size_t)tid * 1024 + cg * 128);
          float acc = 0.f;
#pragma unroll
          for (int i = 0; i < 32; ++i) {
            float4 hv = h4[i], wv = w4[i];
            acc += hv.x * wv.x + hv.y * wv.y + hv.z * wv.z + hv.w * wv.w;
          }
          ast(p3 + l * 16384 + (cg * 8 + b) * 256 + tid, acc);
        }
        __syncthreads();
        if (tid == 0) asti(f3 + b * 8 + cg, seq);
      }
    }  // l

    // ======== S5: head (reduce p3 l=1, out proj, BN, logits, re-embed) ========
    if (sub == 0) {
      waitn(f3 + b * 8, 8, t * 2 + 2);
      rr[tid] = ald(r2red + 2048 + b * 256 + tid);
      __syncthreads();
      ln_row(rr, ln2_g + 256, ln2_b + 256, red);
      float s = 0.f;
#pragma unroll
      for (int cg = 0; cg < 8; ++cg) s += ald(p3 + 16384 + (cg * 8 + b) * 256 + tid);
      float r3v = rr[tid] + s + ffn_b2[256 + tid];
      xs[tid] = r3v;
      ln_row(xs, ln3_g + 256, ln3_b + 256, red);
      float y = dot256(xs, op_w1 + (size_t)tid * 256) + op_b1[tid];
      aux[tid] = fmaxf(y * BNS * bn_g[tid] + bn_b[tid], 0.f);
      __syncthreads();
      if (tid < 128) {
        float v = dot256(aux, op_w2 + (size_t)tid * 256) + op_b2[tid];
        hh[tid] = v;
        outp[((size_t)b * 64 + t) * 128 + tid] = v;
      }
      __syncthreads();
      if (t < 63) {
        const float4* er = (const float4*)(emb_w + (size_t)tid * 128);
        const float4* lr = (const float4*)hh;
        float acc = emb_b[tid];
#pragma unroll
        for (int i = 0; i < 32; ++i) {
          float4 e = er[i], l4 = lr[i];
          acc += e.x * l4.x + e.y * l4.y + e.z * l4.z + e.w * l4.w;
        }
        ast(x0 + b * 256 + tid, acc + pe[(t + 1) * 256 + tid]);
        __syncthreads();
        if (tid == 0) asti(f5 + b, t + 2);
      }
    }
  }  // t
}

// ---------------------------------------------------------------------------

extern "C" void kernel_launch(void* const* d_in, const int* in_sizes, int n_in,
                              void* d_out, int out_size, void* d_ws, size_t ws_size,
                              hipStream_t stream) {
  (void)in_sizes; (void)n_in; (void)out_size; (void)ws_size;
  const float* enc     = (const float*)d_in[0];
  const float* emb_w   = (const float*)d_in[1];
  const float* emb_b   = (const float*)d_in[2];
  const float* sa_wqkv = (const float*)d_in[3];
  const float* sa_bqkv = (const float*)d_in[4];
  const float* sa_wo   = (const float*)d_in[5];
  const float* sa_bo   = (const float*)d_in[6];
  const float* ca_wqkv = (const float*)d_in[7];
  const float* ca_bqkv = (const float*)d_in[8];
  const float* ca_wo   = (const float*)d_in[9];
  const float* ca_bo   = (const float*)d_in[10];
  const float* ln1_g   = (const float*)d_in[11];
  const float* ln1_b   = (const float*)d_in[12];
  const float* ln2_g   = (const float*)d_in[13];
  const float* ln2_b   = (const float*)d_in[14];
  const float* ffn_w1  = (const float*)d_in[15];
  const float* ffn_b1  = (const float*)d_in[16];
  const float* ffn_w2  = (const float*)d_in[17];
  const float* ffn_b2  = (const float*)d_in[18];
  const float* ln3_g   = (const float*)d_in[19];
  const float* ln3_b   = (const float*)d_in[20];
  const float* op_w1   = (const float*)d_in[21];
  const float* op_b1   = (const float*)d_in[22];
  const float* bn_g    = (const float*)d_in[23];
  const float* bn_b    = (const float*)d_in[24];
  const float* op_w2   = (const float*)d_in[25];
  const float* op_b2   = (const float*)d_in[26];

  float* out = (float*)d_out;

  // int region: bar[128], f1[64], f2[64], f3[64], f5[8]  (zeroed every call)
  int* ibase = (int*)d_ws;
  int* bar = ibase;
  int* f1  = ibase + 128;
  int* f2  = ibase + 192;
  int* f3  = ibase + 256;
  int* f5  = ibase + 320;
  hipMemsetAsync(d_ws, 0, 2048, stream);

  float* fb = (float*)d_ws + 512;
  float* pe    = fb;                    // 16384
  float* mk    = pe + 16384;            // 1048576 (2 layers)
  float* mvv   = mk + 1048576;          // 1048576
  float* kc    = mvv + 1048576;         // 262144 (2 layers)
  float* vc    = kc + 262144;           // 262144
  float* x0    = vc + 262144;           // 2048
  float* r1red = x0 + 2048;             // 2048
  float* r2red = r1red + 2048;          // 4096 (2 layers)
  float* r3red = r2red + 4096;          // 2048
  float* p1    = r3red + 2048;          // 16384
  float* p2    = p1 + 16384;            // 16384
  float* p3    = p2 + 16384;            // 32768 (2 layers)

  k_decode<<<64, 256, 0, stream>>>(
      enc, emb_w, emb_b, sa_wqkv, sa_bqkv, sa_wo, sa_bo,
      ca_wqkv, ca_bqkv, ca_wo, ca_bo, ln1_g, ln1_b, ln2_g, ln2_b,
      ffn_w1, ffn_b1, ffn_w2, ffn_b2, ln3_g, ln3_b,
      op_w1, op_b1, bn_g, bn_b, op_w2, op_b2,
      bar, f1, f2, f3, f5, pe, mk, mvv, kc, vc,
      x0, r1red, r2red, r3red, p1, p2, p3, out);
}